// Round 1
// baseline (1275.379 us; speedup 1.0000x reference)
//
#include <hip/hip_runtime.h>

#define BN_EPS 1e-5f

// ---------------- K0: zero BN accumulators ----------------
__global__ __launch_bounds__(1024) void zero_kernel(float* __restrict__ p, int n) {
    int i = blockIdx.x * blockDim.x + threadIdx.x;
    if (i < n) p[i] = 0.f;
}

// ---------------- K1: fused projections (theta/g/phi) + 2x2 maxpool ----------------
// grid: (7 ntiles of 112 hw, 12 mtiles [0-3]=theta [4-7]=g [8-11]=phi, 64 images)
__global__ __launch_bounds__(256) void proj_kernel(
    const float* __restrict__ x,                                  // [64][512][784]
    const float* __restrict__ wth, const float* __restrict__ bth, // [256][512],[256]
    const float* __restrict__ wg,  const float* __restrict__ bg,
    const float* __restrict__ wph, const float* __restrict__ bph,
    float* __restrict__ theta,                                    // [64][256][784]
    float* __restrict__ Gp,                                       // [64][256][196]
    float* __restrict__ Pp)                                       // [64][256][196]
{
    __shared__ float lds[64 * 112];       // reused: staging (2816 f) then out-tile (7168 f)
    float* As = lds;                      // [16][64]  As[k][m]
    float* Bs = lds + 16 * 64;            // [16][112]

    const int tid = threadIdx.x;
    const int tx = tid & 15, ty = tid >> 4;
    const int nt = blockIdx.x, mb = blockIdx.y, n = blockIdx.z;
    const int seg = mb >> 2;
    const int row0 = (mb & 3) << 6;
    const float* W; const float* bias;
    if (seg == 0)      { W = wth; bias = bth; }
    else if (seg == 1) { W = wg;  bias = bg;  }
    else               { W = wph; bias = bph; }
    const int hw0 = nt * 112;
    const float* xn = x + (size_t)n * (512 * 784);

    float acc[4][7];
    #pragma unroll
    for (int i = 0; i < 4; ++i)
        #pragma unroll
        for (int j = 0; j < 7; ++j) acc[i][j] = 0.f;

    const int ar = tid & 63, akq = tid >> 6;
    for (int k0 = 0; k0 < 512; k0 += 16) {
        float4 a4 = *reinterpret_cast<const float4*>(&W[(size_t)(row0 + ar) * 512 + k0 + akq * 4]);
        As[(akq * 4 + 0) * 64 + ar] = a4.x;
        As[(akq * 4 + 1) * 64 + ar] = a4.y;
        As[(akq * 4 + 2) * 64 + ar] = a4.z;
        As[(akq * 4 + 3) * 64 + ar] = a4.w;
        #pragma unroll
        for (int it = 0; it < 7; ++it) {
            int idx = tid + it * 256;
            int kk = idx / 112, j = idx - kk * 112;
            Bs[kk * 112 + j] = xn[(size_t)(k0 + kk) * 784 + hw0 + j];
        }
        __syncthreads();
        #pragma unroll
        for (int k = 0; k < 16; ++k) {
            float4 av = *reinterpret_cast<const float4*>(&As[k * 64 + ty * 4]);
            float a[4] = {av.x, av.y, av.z, av.w};
            float b[7];
            #pragma unroll
            for (int jj = 0; jj < 7; ++jj) b[jj] = Bs[k * 112 + tx + 16 * jj];
            #pragma unroll
            for (int i = 0; i < 4; ++i)
                #pragma unroll
                for (int jj = 0; jj < 7; ++jj) acc[i][jj] = fmaf(a[i], b[jj], acc[i][jj]);
        }
        __syncthreads();
    }

    float bv[4];
    #pragma unroll
    for (int i = 0; i < 4; ++i) bv[i] = bias[row0 + ty * 4 + i];

    if (seg == 0) {
        #pragma unroll
        for (int i = 0; i < 4; ++i)
            #pragma unroll
            for (int jj = 0; jj < 7; ++jj)
                theta[((size_t)n * 256 + row0 + ty * 4 + i) * 784 + hw0 + tx + 16 * jj] =
                    acc[i][jj] + bv[i];
    } else {
        #pragma unroll
        for (int i = 0; i < 4; ++i)
            #pragma unroll
            for (int jj = 0; jj < 7; ++jj)
                lds[(ty * 4 + i) * 112 + tx + 16 * jj] = acc[i][jj] + bv[i];
        __syncthreads();
        float* outp = (seg == 1) ? Gp : Pp;
        #pragma unroll
        for (int t = 0; t < 7; ++t) {            // 64*28 = 1792 = 7*256 pooled outputs
            int idx = tid + t * 256;
            int r = idx / 28, q = idx - r * 28;
            int phl = q / 14, pw = q - phl * 14;
            int j0 = phl * 56 + pw * 2;          // local col of top-left of 2x2 window
            float v0 = lds[r * 112 + j0],      v1 = lds[r * 112 + j0 + 1];
            float v2 = lds[r * 112 + j0 + 28], v3 = lds[r * 112 + j0 + 29];
            float mx = fmaxf(fmaxf(v0, v1), fmaxf(v2, v3));
            outp[((size_t)n * 256 + row0 + r) * 196 + (nt * 2 + phl) * 14 + pw] = mx;
        }
    }
}

// ---------------- K2: S[b] = G[b] * P[b]^T / 1568   (8 x 256x256, K=1568) ----------------
// grid: (4,4,8)
__global__ __launch_bounds__(256) void s_kernel(
    const float* __restrict__ Gp,   // viewed [8][256][1568]
    const float* __restrict__ Pp,
    float* __restrict__ S)          // [8][256][256]
{
    __shared__ float As[32 * 64];   // As[k][m]
    __shared__ float Bs[32 * 64];   // Bs[k][n]
    const int tid = threadIdx.x, tx = tid & 15, ty = tid >> 4;
    const int m0 = blockIdx.x << 6, n0 = blockIdx.y << 6, b = blockIdx.z;
    const float* Gb = Gp + (size_t)b * (256 * 1568);
    const float* Pb = Pp + (size_t)b * (256 * 1568);

    float acc[4][4];
    #pragma unroll
    for (int i = 0; i < 4; ++i)
        #pragma unroll
        for (int j = 0; j < 4; ++j) acc[i][j] = 0.f;

    const int r = tid & 63, kq = tid >> 6;   // each thread: 8 consecutive k at kq*8
    for (int k0 = 0; k0 < 1568; k0 += 32) {
        float4 g0 = *reinterpret_cast<const float4*>(&Gb[(size_t)(m0 + r) * 1568 + k0 + kq * 8]);
        float4 g1 = *reinterpret_cast<const float4*>(&Gb[(size_t)(m0 + r) * 1568 + k0 + kq * 8 + 4]);
        float4 p0 = *reinterpret_cast<const float4*>(&Pb[(size_t)(n0 + r) * 1568 + k0 + kq * 8]);
        float4 p1 = *reinterpret_cast<const float4*>(&Pb[(size_t)(n0 + r) * 1568 + k0 + kq * 8 + 4]);
        As[(kq * 8 + 0) * 64 + r] = g0.x; As[(kq * 8 + 1) * 64 + r] = g0.y;
        As[(kq * 8 + 2) * 64 + r] = g0.z; As[(kq * 8 + 3) * 64 + r] = g0.w;
        As[(kq * 8 + 4) * 64 + r] = g1.x; As[(kq * 8 + 5) * 64 + r] = g1.y;
        As[(kq * 8 + 6) * 64 + r] = g1.z; As[(kq * 8 + 7) * 64 + r] = g1.w;
        Bs[(kq * 8 + 0) * 64 + r] = p0.x; Bs[(kq * 8 + 1) * 64 + r] = p0.y;
        Bs[(kq * 8 + 2) * 64 + r] = p0.z; Bs[(kq * 8 + 3) * 64 + r] = p0.w;
        Bs[(kq * 8 + 4) * 64 + r] = p1.x; Bs[(kq * 8 + 5) * 64 + r] = p1.y;
        Bs[(kq * 8 + 6) * 64 + r] = p1.z; Bs[(kq * 8 + 7) * 64 + r] = p1.w;
        __syncthreads();
        #pragma unroll
        for (int k = 0; k < 32; ++k) {
            float4 a4 = *reinterpret_cast<const float4*>(&As[k * 64 + ty * 4]);
            float4 b4 = *reinterpret_cast<const float4*>(&Bs[k * 64 + tx * 4]);
            float a[4] = {a4.x, a4.y, a4.z, a4.w};
            float bb[4] = {b4.x, b4.y, b4.z, b4.w};
            #pragma unroll
            for (int i = 0; i < 4; ++i)
                #pragma unroll
                for (int j = 0; j < 4; ++j) acc[i][j] = fmaf(a[i], bb[j], acc[i][j]);
        }
        __syncthreads();
    }
    const float sc = 1.f / 1568.f;
    #pragma unroll
    for (int i = 0; i < 4; ++i) {
        float4 o = make_float4(acc[i][0] * sc, acc[i][1] * sc, acc[i][2] * sc, acc[i][3] * sc);
        *reinterpret_cast<float4*>(&S[((size_t)b * 256 + m0 + ty * 4 + i) * 256 + n0 + tx * 4]) = o;
    }
}

// ---------------- K3: Y[b] = S[b] * T[b]   (8 x 256x6272, K=256) ----------------
// grid: (49,4,8)
__global__ __launch_bounds__(256) void y_kernel(
    const float* __restrict__ S,    // [8][256][256]
    const float* __restrict__ T,    // theta viewed [8][256][6272]
    float* __restrict__ Y)          // [8][256][6272]
{
    __shared__ float As[16 * 64];   // As[k][m]
    __shared__ float Bs[16 * 128];  // Bs[k][n]
    const int tid = threadIdx.x, tx = tid & 15, ty = tid >> 4;
    const int nt = blockIdx.x, mt = blockIdx.y, b = blockIdx.z;
    const int m0 = mt << 6, n0 = nt << 7;
    const float* Sb = S + (size_t)b * 65536;
    const float* Tb = T + (size_t)b * (256 * 6272);

    float acc[4][8];
    #pragma unroll
    for (int i = 0; i < 4; ++i)
        #pragma unroll
        for (int j = 0; j < 8; ++j) acc[i][j] = 0.f;

    const int ar = tid & 63, akq = tid >> 6;
    for (int k0 = 0; k0 < 256; k0 += 16) {
        float4 a4 = *reinterpret_cast<const float4*>(&Sb[(size_t)(m0 + ar) * 256 + k0 + akq * 4]);
        As[(akq * 4 + 0) * 64 + ar] = a4.x;
        As[(akq * 4 + 1) * 64 + ar] = a4.y;
        As[(akq * 4 + 2) * 64 + ar] = a4.z;
        As[(akq * 4 + 3) * 64 + ar] = a4.w;
        #pragma unroll
        for (int it = 0; it < 2; ++it) {
            int idx = tid + (it << 8);
            int kk = idx >> 5, j4 = (idx & 31) << 2;
            *reinterpret_cast<float4*>(&Bs[kk * 128 + j4]) =
                *reinterpret_cast<const float4*>(&Tb[(size_t)(k0 + kk) * 6272 + n0 + j4]);
        }
        __syncthreads();
        #pragma unroll
        for (int k = 0; k < 16; ++k) {
            float4 av = *reinterpret_cast<const float4*>(&As[k * 64 + ty * 4]);
            float a[4] = {av.x, av.y, av.z, av.w};
            float bb[8];
            #pragma unroll
            for (int jj = 0; jj < 8; ++jj) bb[jj] = Bs[k * 128 + tx + 16 * jj];
            #pragma unroll
            for (int i = 0; i < 4; ++i)
                #pragma unroll
                for (int jj = 0; jj < 8; ++jj) acc[i][jj] = fmaf(a[i], bb[jj], acc[i][jj]);
        }
        __syncthreads();
    }
    #pragma unroll
    for (int i = 0; i < 4; ++i)
        #pragma unroll
        for (int jj = 0; jj < 8; ++jj)
            Y[((size_t)b * 256 + m0 + ty * 4 + i) * 6272 + n0 + tx + 16 * jj] = acc[i][jj];
}

// ---------------- K4: Z = wW*Y + bW, with fused BN partial sums ----------------
// grid: (7, 8, 64)
__global__ __launch_bounds__(256) void zconv_kernel(
    const float* __restrict__ Y,    // [64][256][784]
    const float* __restrict__ wW,   // [512][256]
    const float* __restrict__ bW,   // [512]
    float* __restrict__ Z,          // [64][512][784]
    float* __restrict__ sumBuf, float* __restrict__ sqBuf)
{
    __shared__ float As[16 * 64];
    __shared__ float Bs[16 * 112];
    __shared__ float rsum[64], rsq[64];
    const int tid = threadIdx.x, tx = tid & 15, ty = tid >> 4;
    const int nt = blockIdx.x, mt = blockIdx.y, n = blockIdx.z;
    const int row0 = mt << 6;
    const int hw0 = nt * 112;
    const float* Yn = Y + (size_t)n * (256 * 784);

    float acc[4][7];
    #pragma unroll
    for (int i = 0; i < 4; ++i)
        #pragma unroll
        for (int j = 0; j < 7; ++j) acc[i][j] = 0.f;

    const int ar = tid & 63, akq = tid >> 6;
    for (int k0 = 0; k0 < 256; k0 += 16) {
        float4 a4 = *reinterpret_cast<const float4*>(&wW[(size_t)(row0 + ar) * 256 + k0 + akq * 4]);
        As[(akq * 4 + 0) * 64 + ar] = a4.x;
        As[(akq * 4 + 1) * 64 + ar] = a4.y;
        As[(akq * 4 + 2) * 64 + ar] = a4.z;
        As[(akq * 4 + 3) * 64 + ar] = a4.w;
        #pragma unroll
        for (int it = 0; it < 7; ++it) {
            int idx = tid + it * 256;
            int kk = idx / 112, j = idx - kk * 112;
            Bs[kk * 112 + j] = Yn[(size_t)(k0 + kk) * 784 + hw0 + j];
        }
        __syncthreads();
        #pragma unroll
        for (int k = 0; k < 16; ++k) {
            float4 av = *reinterpret_cast<const float4*>(&As[k * 64 + ty * 4]);
            float a[4] = {av.x, av.y, av.z, av.w};
            float b[7];
            #pragma unroll
            for (int jj = 0; jj < 7; ++jj) b[jj] = Bs[k * 112 + tx + 16 * jj];
            #pragma unroll
            for (int i = 0; i < 4; ++i)
                #pragma unroll
                for (int jj = 0; jj < 7; ++jj) acc[i][jj] = fmaf(a[i], b[jj], acc[i][jj]);
        }
        __syncthreads();
    }

    float s1[4] = {0.f, 0.f, 0.f, 0.f}, s2[4] = {0.f, 0.f, 0.f, 0.f};
    #pragma unroll
    for (int i = 0; i < 4; ++i) {
        float bvi = bW[row0 + ty * 4 + i];
        #pragma unroll
        for (int jj = 0; jj < 7; ++jj) {
            float z = acc[i][jj] + bvi;
            Z[((size_t)n * 512 + row0 + ty * 4 + i) * 784 + hw0 + tx + 16 * jj] = z;
            s1[i] += z;
            s2[i] += z * z;
        }
    }
    #pragma unroll
    for (int off = 1; off < 16; off <<= 1) {
        #pragma unroll
        for (int i = 0; i < 4; ++i) {
            s1[i] += __shfl_xor(s1[i], off);
            s2[i] += __shfl_xor(s2[i], off);
        }
    }
    if (tx == 0) {
        #pragma unroll
        for (int i = 0; i < 4; ++i) { rsum[ty * 4 + i] = s1[i]; rsq[ty * 4 + i] = s2[i]; }
    }
    __syncthreads();
    if (tid < 64) {
        atomicAdd(&sumBuf[row0 + tid], rsum[tid]);
        atomicAdd(&sqBuf[row0 + tid], rsq[tid]);
    }
}

// ---------------- K5: BN finalize -> per-channel scale/shift ----------------
__global__ __launch_bounds__(512) void bn_finalize(
    const float* __restrict__ sumBuf, const float* __restrict__ sqBuf,
    const float* __restrict__ gamma, const float* __restrict__ beta,
    float* __restrict__ scale, float* __restrict__ shift)
{
    int c = threadIdx.x;
    if (c < 512) {
        const float invN = 1.f / 50176.f;   // 64*784
        float mean = sumBuf[c] * invN;
        float var  = sqBuf[c] * invN - mean * mean;   // biased variance (torch semantics)
        float inv  = rsqrtf(var + BN_EPS);
        float sc = gamma[c] * inv;
        scale[c] = sc;
        shift[c] = beta[c] - mean * sc;
    }
}

// ---------------- K6: out = Z*scale + shift + x ----------------
__global__ __launch_bounds__(256) void bn_apply(
    const float* __restrict__ Z, const float* __restrict__ x,
    const float* __restrict__ scale, const float* __restrict__ shift,
    float* __restrict__ out, int total4)
{
    int idx = blockIdx.x * 256 + threadIdx.x;
    if (idx < total4) {
        int co = (idx / 196) & 511;              // 784/4 = 196 float4 per (n,co) row
        float4 z = reinterpret_cast<const float4*>(Z)[idx];
        float4 xv = reinterpret_cast<const float4*>(x)[idx];
        float sc = scale[co], sh = shift[co];
        float4 o;
        o.x = fmaf(z.x, sc, sh) + xv.x;
        o.y = fmaf(z.y, sc, sh) + xv.y;
        o.z = fmaf(z.z, sc, sh) + xv.z;
        o.w = fmaf(z.w, sc, sh) + xv.w;
        reinterpret_cast<float4*>(out)[idx] = o;
    }
}

extern "C" void kernel_launch(void* const* d_in, const int* in_sizes, int n_in,
                              void* d_out, int out_size, void* d_ws, size_t ws_size,
                              hipStream_t stream)
{
    const float* x     = (const float*)d_in[0];
    const float* wg    = (const float*)d_in[1];
    const float* bg    = (const float*)d_in[2];
    const float* wth   = (const float*)d_in[3];
    const float* bth   = (const float*)d_in[4];
    const float* wph   = (const float*)d_in[5];
    const float* bph   = (const float*)d_in[6];
    const float* wW    = (const float*)d_in[7];
    const float* bW    = (const float*)d_in[8];
    const float* gamma = (const float*)d_in[9];
    const float* beta  = (const float*)d_in[10];
    float* out = (float*)d_out;
    float* ws  = (float*)d_ws;

    // workspace layout (floats); Z aliases theta/G/P/S (dead by the time Z is written)
    float* Yb    = ws;                 // 12,845,056  [64][256][784]
    float* theta = ws + 12845056;      // 12,845,056  [64][256][784]
    float* Gp    = ws + 25690112;      //  3,211,264  [64][256][196]
    float* Pp    = ws + 28901376;      //  3,211,264
    float* Sb    = ws + 32112640;      //    524,288  [8][256][256]
    float* Zb    = ws + 12845056;      // 25,690,112  [64][512][784] (alias)
    float* stats = ws + 38535168;      // sum[512]|sq[512]|scale[512]|shift[512]

    zero_kernel<<<1, 1024, 0, stream>>>(stats, 1024);
    proj_kernel<<<dim3(7, 12, 64), 256, 0, stream>>>(x, wth, bth, wg, bg, wph, bph,
                                                     theta, Gp, Pp);
    s_kernel<<<dim3(4, 4, 8), 256, 0, stream>>>(Gp, Pp, Sb);
    y_kernel<<<dim3(49, 4, 8), 256, 0, stream>>>(Sb, theta, Yb);
    zconv_kernel<<<dim3(7, 8, 64), 256, 0, stream>>>(Yb, wW, bW, Zb, stats, stats + 512);
    bn_finalize<<<1, 512, 0, stream>>>(stats, stats + 512, gamma, beta,
                                       stats + 1024, stats + 1536);
    bn_apply<<<25088, 256, 0, stream>>>(Zb, x, stats + 1024, stats + 1536, out, 6422528);
}

// Round 2
// 626.214 us; speedup vs baseline: 2.0366x; 2.0366x over previous
//
#include <hip/hip_runtime.h>
#include <stdint.h>

#define BN_EPS 1e-5f

typedef float  f32x4  __attribute__((ext_vector_type(4)));
typedef short  bf16x8 __attribute__((ext_vector_type(8)));

#define MFMA16(a, b, c) __builtin_amdgcn_mfma_f32_16x16x32_bf16((a), (b), (c), 0, 0, 0)

#define GLD16(gsrc, ldst)                                                              \
    __builtin_amdgcn_global_load_lds(                                                  \
        (const __attribute__((address_space(1))) uint32_t*)(gsrc),                     \
        (__attribute__((address_space(3))) uint32_t*)(ldst), 16, 0, 0)

__device__ __forceinline__ unsigned short f2bf(float f) {
    union { float f; uint32_t u; } v; v.f = f;
    uint32_t u = v.u;
    u += 0x7FFF + ((u >> 16) & 1);          // RNE
    return (unsigned short)(u >> 16);
}
__device__ __forceinline__ float bf2f(unsigned short u) {
    union { uint32_t u; float f; } v; v.u = ((uint32_t)u) << 16; return v.f;
}

// ---------------- zero ----------------
__global__ __launch_bounds__(1024) void zero_kernel(float* __restrict__ p, int n) {
    int i = blockIdx.x * blockDim.x + threadIdx.x;
    if (i < n) p[i] = 0.f;
}

// ---------------- cast weights (wth/wg/wph straight, wW permuted) ----------------
__global__ __launch_bounds__(256) void castw_kernel(
    const float* __restrict__ wth, const float* __restrict__ wg,
    const float* __restrict__ wph, const float* __restrict__ wW,
    unsigned short* __restrict__ wthb, unsigned short* __restrict__ wgb,
    unsigned short* __restrict__ wphb, unsigned short* __restrict__ wW2b)
{
    int i = blockIdx.x * 256 + threadIdx.x;
    if (i < 131072) wthb[i] = f2bf(wth[i]);
    else if (i < 262144) wgb[i - 131072] = f2bf(wg[i - 131072]);
    else if (i < 393216) wphb[i - 262144] = f2bf(wph[i - 262144]);
    else {
        int j = i - 393216;                  // [co][k'] with k' = q*32 + a
        int co = j >> 8, k = j & 255;
        int q = k >> 5, a = k & 31;
        wW2b[j] = f2bf(wW[(co << 8) + (a << 3) + q]);
    }
}

// ---------------- cast + transpose x -> xT[(n*784+hw)][512] bf16 ----------------
__global__ __launch_bounds__(256) void castx_kernel(
    const float* __restrict__ x, unsigned short* __restrict__ xT)
{
    __shared__ float lds[64 * 65];
    const int tid = threadIdx.x;
    const int ht = blockIdx.x, ct = blockIdx.y, n = blockIdx.z;
    const int hw0 = ht << 6, ch0 = ct << 6;
    const float* xn = x + (size_t)n * 401408;
    #pragma unroll
    for (int it = 0; it < 16; ++it) {
        int idx = tid + (it << 8);
        int r = idx >> 6, cw = idx & 63;
        int hw = hw0 + cw;
        if (hw < 784) lds[r * 65 + cw] = xn[(size_t)(ch0 + r) * 784 + hw];
    }
    __syncthreads();
    #pragma unroll
    for (int it = 0; it < 8; ++it) {
        int idx = tid + (it << 8);
        int hl = idx >> 5, c2 = (idx & 31) << 1;
        int hw = hw0 + hl;
        if (hw < 784) {
            uint32_t lo = f2bf(lds[c2 * 65 + hl]);
            uint32_t hi = f2bf(lds[(c2 + 1) * 65 + hl]);
            *(uint32_t*)(xT + ((size_t)(n * 784 + hw) << 9) + ch0 + c2) = lo | (hi << 16);
        }
    }
}

// ---------------- proj_theta: theta = wth * x, output thetaT[seg][t][i] ----------------
// grid (392, 2), block 256 (4 waves 2x2), BM=BN=128, BK=32, K=512
__global__ __launch_bounds__(256) void proj_theta_kernel(
    const unsigned short* __restrict__ xT, const unsigned short* __restrict__ wthb,
    const float* __restrict__ bth, unsigned short* __restrict__ thetaT)
{
    __shared__ char smem[32768];             // dbuf 2 x (A 8K | B 8K); epilogue bounce 32K
    const int tid = threadIdx.x, l = tid & 63, w = tid >> 6;
    const int jt = blockIdx.x, mb = blockIdx.y;
    const int m0 = mb << 7, j0 = jt << 7;
    const int wm = w >> 1, wn = w & 1;

    const unsigned short* srcA[2]; const unsigned short* srcB[2];
    #pragma unroll
    for (int i = 0; i < 2; ++i) {
        int c = (w << 7) + (i << 6) + l;     // chunk id 0..511
        int m = c & 127, kc = c >> 7;
        srcA[i] = wthb + (((size_t)(m0 + m)) << 9) + (kc << 3);
        srcB[i] = xT + (((size_t)(j0 + m)) << 9) + (kc << 3);
    }
    // prologue stage step 0 -> buf 0
    #pragma unroll
    for (int i = 0; i < 2; ++i) {
        GLD16(srcA[i], smem + (w << 11) + (i << 10));
        GLD16(srcB[i], smem + 8192 + (w << 11) + (i << 10));
        srcA[i] += 32; srcB[i] += 32;
    }
    f32x4 acc[4][4] = {};
    const int fr = ((l >> 4) << 7) + (l & 15);
    for (int s = 0; s < 16; ++s) {
        __syncthreads();
        char* cur = smem + ((s & 1) << 14);
        if (s + 1 < 16) {
            char* nxt = smem + (((s + 1) & 1) << 14);
            #pragma unroll
            for (int i = 0; i < 2; ++i) {
                GLD16(srcA[i], nxt + (w << 11) + (i << 10));
                GLD16(srcB[i], nxt + 8192 + (w << 11) + (i << 10));
                srcA[i] += 32; srcB[i] += 32;
            }
        }
        bf16x8 a[4], b[4];
        #pragma unroll
        for (int mf = 0; mf < 4; ++mf)
            a[mf] = *(const bf16x8*)(cur + ((fr + (wm << 6) + (mf << 4)) << 4));
        #pragma unroll
        for (int nf = 0; nf < 4; ++nf)
            b[nf] = *(const bf16x8*)(cur + 8192 + ((fr + (wn << 6) + (nf << 4)) << 4));
        #pragma unroll
        for (int mf = 0; mf < 4; ++mf)
            #pragma unroll
            for (int nf = 0; nf < 4; ++nf)
                acc[mf][nf] = MFMA16(a[mf], b[nf], acc[mf][nf]);
    }
    __syncthreads();
    // bounce tile [c_local 128][j_local 128] bf16
    unsigned short* lds16 = (unsigned short*)smem;
    #pragma unroll
    for (int mf = 0; mf < 4; ++mf) {
        int cbase = (wm << 6) + (mf << 4) + ((l >> 4) << 2);
        #pragma unroll
        for (int r = 0; r < 4; ++r) {
            float bv = bth[m0 + cbase + r];
            #pragma unroll
            for (int nf = 0; nf < 4; ++nf) {
                int jl = (wn << 6) + (nf << 4) + (l & 15);
                lds16[(cbase + r) * 128 + jl] = f2bf(acc[mf][nf][r] + bv);
            }
        }
    }
    __syncthreads();
    // scatter to thetaT[seg][t=q*784+hw][i]; i = (n&7)*32 + mb*16 + h*8 + e
    const int jl = tid >> 1, h = tid & 1;
    const int j = j0 + jl;
    const int n = j / 784;
    const int hw = j - n * 784;
    const int seg = n >> 3;
    unsigned short* ob = thetaT + (size_t)seg * 1605632 + ((n & 7) << 5) + (mb << 4) + (h << 3);
    #pragma unroll
    for (int q = 0; q < 8; ++q) {
        uint32_t u[8];
        #pragma unroll
        for (int e = 0; e < 8; ++e)
            u[e] = lds16[(((h << 3) + e) * 8 + q) * 128 + jl];
        uint4 pk;
        pk.x = u[0] | (u[1] << 16); pk.y = u[2] | (u[3] << 16);
        pk.z = u[4] | (u[5] << 16); pk.w = u[6] | (u[7] << 16);
        *(uint4*)(ob + (size_t)(q * 784 + hw) * 256) = pk;
    }
}

// ---------------- proj_gp: g/phi conv + 2x2 maxpool -> Gv/Pv (ref raw layout) ----------------
// grid (7, 4, 64): x = hw-tile(112), y = mb (0-1 g, 2-3 phi), z = image. BM=128, BN=112
__global__ __launch_bounds__(256) void proj_gp_kernel(
    const unsigned short* __restrict__ xT,
    const unsigned short* __restrict__ wgb, const unsigned short* __restrict__ wphb,
    const float* __restrict__ bg, const float* __restrict__ bph,
    unsigned short* __restrict__ Gv, unsigned short* __restrict__ Pv)
{
    __shared__ char smem[30720];             // dbuf 2 x (A 8192 | B 7168)
    const int tid = threadIdx.x, l = tid & 63, w = tid >> 6;
    const int jt = blockIdx.x, mb = blockIdx.y, n = blockIdx.z;
    const int isP = mb >> 1, row0 = (mb & 1) << 7;
    const unsigned short* Wb = isP ? wphb : wgb;
    const int hw0 = jt * 112;

    const unsigned short* srcA[2]; const unsigned short* srcB[2];
    #pragma unroll
    for (int i = 0; i < 2; ++i) {
        int ca = (w << 7) + (i << 6) + l;
        srcA[i] = Wb + (((size_t)(row0 + (ca & 127))) << 9) + ((ca >> 7) << 3);
        int cb = w * 112 + (i << 6) + l;
        int jj = cb % 112, kc = cb / 112;
        srcB[i] = xT + (((size_t)(n * 784 + hw0 + jj)) << 9) + (kc << 3);
    }
    #pragma unroll
    for (int i = 0; i < 2; ++i) {
        GLD16(srcA[i], smem + (w << 11) + (i << 10));
        if (i == 0 || l < 48)
            GLD16(srcB[i], smem + 8192 + w * 1792 + (i << 10));
        srcA[i] += 32; srcB[i] += 32;
    }
    f32x4 acc[2][7] = {};
    for (int s = 0; s < 16; ++s) {
        __syncthreads();
        char* cur = smem + (s & 1) * 15360;
        if (s + 1 < 16) {
            char* nxt = smem + ((s + 1) & 1) * 15360;
            #pragma unroll
            for (int i = 0; i < 2; ++i) {
                GLD16(srcA[i], nxt + (w << 11) + (i << 10));
                if (i == 0 || l < 48)
                    GLD16(srcB[i], nxt + 8192 + w * 1792 + (i << 10));
                srcA[i] += 32; srcB[i] += 32;
            }
        }
        bf16x8 a[2], b[7];
        #pragma unroll
        for (int mf = 0; mf < 2; ++mf)
            a[mf] = *(const bf16x8*)(cur + ((((l >> 4) << 7) + (w << 5) + (mf << 4) + (l & 15)) << 4));
        #pragma unroll
        for (int nf = 0; nf < 7; ++nf)
            b[nf] = *(const bf16x8*)(cur + 8192 + ((((l >> 4) * 112) + (nf << 4) + (l & 15)) << 4));
        #pragma unroll
        for (int mf = 0; mf < 2; ++mf)
            #pragma unroll
            for (int nf = 0; nf < 7; ++nf)
                acc[mf][nf] = MFMA16(a[mf], b[nf], acc[mf][nf]);
    }
    __syncthreads();
    unsigned short* lds16 = (unsigned short*)smem;   // [c 128][hw 112]
    #pragma unroll
    for (int mf = 0; mf < 2; ++mf) {
        int cbase = (w << 5) + (mf << 4) + ((l >> 4) << 2);
        #pragma unroll
        for (int r = 0; r < 4; ++r)
            #pragma unroll
            for (int nf = 0; nf < 7; ++nf) {
                int jl = (nf << 4) + (l & 15);
                lds16[(cbase + r) * 112 + jl] = f2bf(acc[mf][nf][r]);
            }
    }
    __syncthreads();
    // pool 2x2 + bias; write ref-raw layout: seg*401408 + vr*1568 + vp
    const int c_l = tid >> 1, ph_l = tid & 1;
    const int c = row0 + c_l;
    const float bv = (isP ? bph : bg)[c];
    const int seg = n >> 3;
    const int vr = ((n & 7) << 5) + (c >> 3);
    const int vp0 = (c & 7) * 196 + ((jt << 1) + ph_l) * 14;
    unsigned short* outp = (isP ? Pv : Gv) + (size_t)seg * 401408 + (size_t)vr * 1568 + vp0;
    const unsigned short* rowA = lds16 + c_l * 112 + ph_l * 56;
    #pragma unroll
    for (int pw = 0; pw < 14; pw += 2) {
        unsigned short o[2];
        #pragma unroll
        for (int t2 = 0; t2 < 2; ++t2) {
            int wb = (pw + t2) << 1;
            float v0 = bf2f(rowA[wb]),     v1 = bf2f(rowA[wb + 1]);
            float v2 = bf2f(rowA[wb + 28]), v3 = bf2f(rowA[wb + 29]);
            o[t2] = f2bf(fmaxf(fmaxf(v0, v1), fmaxf(v2, v3)) + bv);
        }
        *(ushort2*)(outp + pw) = make_ushort2(o[0], o[1]);
    }
}

// ---------------- s_kernel: S = G * P^T / 1568, bf16 out ----------------
// grid (2, 2, 8), BM=BN=128, K=1568 (49 steps)
__global__ __launch_bounds__(256) void s_kernel(
    const unsigned short* __restrict__ Gv, const unsigned short* __restrict__ Pv,
    unsigned short* __restrict__ Sb)
{
    __shared__ char smem[32768];
    const int tid = threadIdx.x, l = tid & 63, w = tid >> 6;
    const int m0 = blockIdx.x << 7, n0 = blockIdx.y << 7, seg = blockIdx.z;
    const int wm = w >> 1, wn = w & 1;
    const unsigned short* srcA[2]; const unsigned short* srcB[2];
    #pragma unroll
    for (int i = 0; i < 2; ++i) {
        int c = (w << 7) + (i << 6) + l;
        srcA[i] = Gv + (size_t)seg * 401408 + (size_t)(m0 + (c & 127)) * 1568 + ((c >> 7) << 3);
        srcB[i] = Pv + (size_t)seg * 401408 + (size_t)(n0 + (c & 127)) * 1568 + ((c >> 7) << 3);
    }
    #pragma unroll
    for (int i = 0; i < 2; ++i) {
        GLD16(srcA[i], smem + (w << 11) + (i << 10));
        GLD16(srcB[i], smem + 8192 + (w << 11) + (i << 10));
        srcA[i] += 32; srcB[i] += 32;
    }
    f32x4 acc[4][4] = {};
    const int fr = ((l >> 4) << 7) + (l & 15);
    for (int s = 0; s < 49; ++s) {
        __syncthreads();
        char* cur = smem + ((s & 1) << 14);
        if (s + 1 < 49) {
            char* nxt = smem + (((s + 1) & 1) << 14);
            #pragma unroll
            for (int i = 0; i < 2; ++i) {
                GLD16(srcA[i], nxt + (w << 11) + (i << 10));
                GLD16(srcB[i], nxt + 8192 + (w << 11) + (i << 10));
                srcA[i] += 32; srcB[i] += 32;
            }
        }
        bf16x8 a[4], b[4];
        #pragma unroll
        for (int mf = 0; mf < 4; ++mf)
            a[mf] = *(const bf16x8*)(cur + ((fr + (wm << 6) + (mf << 4)) << 4));
        #pragma unroll
        for (int nf = 0; nf < 4; ++nf)
            b[nf] = *(const bf16x8*)(cur + 8192 + ((fr + (wn << 6) + (nf << 4)) << 4));
        #pragma unroll
        for (int mf = 0; mf < 4; ++mf)
            #pragma unroll
            for (int nf = 0; nf < 4; ++nf)
                acc[mf][nf] = MFMA16(a[mf], b[nf], acc[mf][nf]);
    }
    __syncthreads();
    unsigned short* lds16 = (unsigned short*)smem;   // [c 128][i 128]
    const float sc = 1.f / 1568.f;
    #pragma unroll
    for (int mf = 0; mf < 4; ++mf) {
        int cbase = (wm << 6) + (mf << 4) + ((l >> 4) << 2);
        #pragma unroll
        for (int r = 0; r < 4; ++r)
            #pragma unroll
            for (int nf = 0; nf < 4; ++nf) {
                int il = (wn << 6) + (nf << 4) + (l & 15);
                lds16[(cbase + r) * 128 + il] = f2bf(acc[mf][nf][r] * sc);
            }
    }
    __syncthreads();
    #pragma unroll
    for (int it = 0; it < 8; ++it) {
        int idx = tid + (it << 8);
        int crow = idx >> 4, ic = idx & 15;
        uint4 pk = *(const uint4*)(lds16 + crow * 128 + (ic << 3));
        *(uint4*)(Sb + (size_t)seg * 65536 + (size_t)(m0 + crow) * 256 + n0 + (ic << 3)) = pk;
    }
}

// ---------------- y_kernel: Y = S * Tv -> YT2[seg][t][c] bf16 ----------------
// grid (49, 2, 8), BM=BN=128, K=256 (8 steps)
__global__ __launch_bounds__(256) void y_kernel(
    const unsigned short* __restrict__ Sb, const unsigned short* __restrict__ thetaT,
    unsigned short* __restrict__ YT2)
{
    __shared__ char smem[32768];
    const int tid = threadIdx.x, l = tid & 63, w = tid >> 6;
    const int jt = blockIdx.x, mt = blockIdx.y, seg = blockIdx.z;
    const int m0 = mt << 7, t0 = jt << 7;
    const int wm = w >> 1, wn = w & 1;
    const unsigned short* srcA[2]; const unsigned short* srcB[2];
    #pragma unroll
    for (int i = 0; i < 2; ++i) {
        int c = (w << 7) + (i << 6) + l;
        srcA[i] = Sb + (size_t)seg * 65536 + (size_t)(m0 + (c & 127)) * 256 + ((c >> 7) << 3);
        srcB[i] = thetaT + (size_t)seg * 1605632 + (size_t)(t0 + (c & 127)) * 256 + ((c >> 7) << 3);
    }
    #pragma unroll
    for (int i = 0; i < 2; ++i) {
        GLD16(srcA[i], smem + (w << 11) + (i << 10));
        GLD16(srcB[i], smem + 8192 + (w << 11) + (i << 10));
        srcA[i] += 32; srcB[i] += 32;
    }
    f32x4 acc[4][4] = {};
    const int fr = ((l >> 4) << 7) + (l & 15);
    for (int s = 0; s < 8; ++s) {
        __syncthreads();
        char* cur = smem + ((s & 1) << 14);
        if (s + 1 < 8) {
            char* nxt = smem + (((s + 1) & 1) << 14);
            #pragma unroll
            for (int i = 0; i < 2; ++i) {
                GLD16(srcA[i], nxt + (w << 11) + (i << 10));
                GLD16(srcB[i], nxt + 8192 + (w << 11) + (i << 10));
                srcA[i] += 32; srcB[i] += 32;
            }
        }
        bf16x8 a[4], b[4];
        #pragma unroll
        for (int mf = 0; mf < 4; ++mf)
            a[mf] = *(const bf16x8*)(cur + ((fr + (wm << 6) + (mf << 4)) << 4));
        #pragma unroll
        for (int nf = 0; nf < 4; ++nf)
            b[nf] = *(const bf16x8*)(cur + 8192 + ((fr + (wn << 6) + (nf << 4)) << 4));
        #pragma unroll
        for (int mf = 0; mf < 4; ++mf)
            #pragma unroll
            for (int nf = 0; nf < 4; ++nf)
                acc[mf][nf] = MFMA16(a[mf], b[nf], acc[mf][nf]);
    }
    __syncthreads();
    unsigned short* lds16 = (unsigned short*)smem;   // [c 128][t 128]
    #pragma unroll
    for (int mf = 0; mf < 4; ++mf) {
        int cbase = (wm << 6) + (mf << 4) + ((l >> 4) << 2);
        #pragma unroll
        for (int r = 0; r < 4; ++r)
            #pragma unroll
            for (int nf = 0; nf < 4; ++nf) {
                int jl = (wn << 6) + (nf << 4) + (l & 15);
                lds16[(cbase + r) * 128 + jl] = f2bf(acc[mf][nf][r]);
            }
    }
    __syncthreads();
    #pragma unroll
    for (int it = 0; it < 8; ++it) {
        int idx = tid + (it << 8);
        int jl = idx >> 4, cc = idx & 15;
        uint32_t u[8];
        #pragma unroll
        for (int e = 0; e < 8; ++e)
            u[e] = lds16[((cc << 3) + e) * 128 + jl];
        uint4 pk;
        pk.x = u[0] | (u[1] << 16); pk.y = u[2] | (u[3] << 16);
        pk.z = u[4] | (u[5] << 16); pk.w = u[6] | (u[7] << 16);
        *(uint4*)(YT2 + (size_t)seg * 1605632 + (size_t)(t0 + jl) * 256 + m0 + (cc << 3)) = pk;
    }
}

// ---------------- zconv: Z[j][co] = wW2 * YT2 + bW, fused BN partial sums ----------------
// grid (392, 4), BM=128 co, BN=128 j, K=256 (8 steps over q)
__global__ __launch_bounds__(256) void zconv_kernel(
    const unsigned short* __restrict__ YT2, const unsigned short* __restrict__ wW2b,
    const float* __restrict__ bW, float* __restrict__ Z,
    float* __restrict__ sumB, float* __restrict__ sqB)
{
    __shared__ char smem[32768];
    const int tid = threadIdx.x, l = tid & 63, w = tid >> 6;
    const int jt = blockIdx.x, mt = blockIdx.y;
    const int m0 = mt << 7, j0 = jt << 7;
    const int wm = w >> 1, wn = w & 1;
    const unsigned short* srcA[2]; const unsigned short* srcB[2];
    #pragma unroll
    for (int i = 0; i < 2; ++i) {
        int c = (w << 7) + (i << 6) + l;
        int jj = c & 127, kc = c >> 7;
        srcA[i] = wW2b + (size_t)(m0 + jj) * 256 + (kc << 3);
        int j = j0 + jj;
        int nimg = j / 784;
        int hw = j - nimg * 784;
        srcB[i] = YT2 + (size_t)(nimg >> 3) * 1605632 + (size_t)hw * 256 + ((nimg & 7) << 5) + (kc << 3);
    }
    #pragma unroll
    for (int i = 0; i < 2; ++i) {
        GLD16(srcA[i], smem + (w << 11) + (i << 10));
        GLD16(srcB[i], smem + 8192 + (w << 11) + (i << 10));
        srcA[i] += 32; srcB[i] += 200704;       // next q: +784*256 elements
    }
    f32x4 acc[4][4] = {};
    const int fr = ((l >> 4) << 7) + (l & 15);
    for (int s = 0; s < 8; ++s) {
        __syncthreads();
        char* cur = smem + ((s & 1) << 14);
        if (s + 1 < 8) {
            char* nxt = smem + (((s + 1) & 1) << 14);
            #pragma unroll
            for (int i = 0; i < 2; ++i) {
                GLD16(srcA[i], nxt + (w << 11) + (i << 10));
                GLD16(srcB[i], nxt + 8192 + (w << 11) + (i << 10));
                srcA[i] += 32; srcB[i] += 200704;
            }
        }
        bf16x8 a[4], b[4];
        #pragma unroll
        for (int mf = 0; mf < 4; ++mf)
            a[mf] = *(const bf16x8*)(cur + ((fr + (wm << 6) + (mf << 4)) << 4));
        #pragma unroll
        for (int nf = 0; nf < 4; ++nf)
            b[nf] = *(const bf16x8*)(cur + 8192 + ((fr + (wn << 6) + (nf << 4)) << 4));
        #pragma unroll
        for (int mf = 0; mf < 4; ++mf)
            #pragma unroll
            for (int nf = 0; nf < 4; ++nf)
                acc[mf][nf] = MFMA16(a[mf], b[nf], acc[mf][nf]);
    }
    // epilogue: Z stores + per-channel sums
    #pragma unroll
    for (int mf = 0; mf < 4; ++mf) {
        int co = m0 + (wm << 6) + (mf << 4) + ((l >> 4) << 2);
        float4 bv = *(const float4*)&bW[co];
        float s1[4] = {0, 0, 0, 0}, s2[4] = {0, 0, 0, 0};
        #pragma unroll
        for (int nf = 0; nf < 4; ++nf) {
            int j = j0 + (wn << 6) + (nf << 4) + (l & 15);
            float4 o;
            o.x = acc[mf][nf][0] + bv.x; o.y = acc[mf][nf][1] + bv.y;
            o.z = acc[mf][nf][2] + bv.z; o.w = acc[mf][nf][3] + bv.w;
            *(float4*)&Z[(size_t)j * 512 + co] = o;
            s1[0] += o.x; s2[0] += o.x * o.x;
            s1[1] += o.y; s2[1] += o.y * o.y;
            s1[2] += o.z; s2[2] += o.z * o.z;
            s1[3] += o.w; s2[3] += o.w * o.w;
        }
        #pragma unroll
        for (int off = 1; off < 16; off <<= 1)
            #pragma unroll
            for (int r = 0; r < 4; ++r) {
                s1[r] += __shfl_xor(s1[r], off);
                s2[r] += __shfl_xor(s2[r], off);
            }
        if ((l & 15) == 0)
            #pragma unroll
            for (int r = 0; r < 4; ++r) {
                atomicAdd(&sumB[co + r], s1[r]);
                atomicAdd(&sqB[co + r], s2[r]);
            }
    }
}

// ---------------- BN finalize ----------------
__global__ __launch_bounds__(512) void bn_finalize(
    const float* __restrict__ sumB, const float* __restrict__ sqB,
    const float* __restrict__ gamma, const float* __restrict__ beta,
    float* __restrict__ scale, float* __restrict__ shift)
{
    int c = threadIdx.x;
    if (c < 512) {
        const float invN = 1.f / 50176.f;
        float mean = sumB[c] * invN;
        float var = sqB[c] * invN - mean * mean;
        float inv = rsqrtf(var + BN_EPS);
        float sc = gamma[c] * inv;
        scale[c] = sc;
        shift[c] = beta[c] - mean * sc;
    }
}

// ---------------- bn_apply: out[n][co][hw] = Z[j][co]*scale + shift + x ----------------
// grid (392, 8): tile 128 j x 64 co
__global__ __launch_bounds__(256) void bn_apply(
    const float* __restrict__ Z, const float* __restrict__ x,
    const float* __restrict__ scale, const float* __restrict__ shift,
    float* __restrict__ out)
{
    __shared__ float lds[128 * 65];
    const int tid = threadIdx.x;
    const int j0 = blockIdx.x << 7, co0 = blockIdx.y << 6;
    #pragma unroll
    for (int it = 0; it < 8; ++it) {
        int idx = tid + (it << 8);
        int jl = idx >> 4, c4 = (idx & 15) << 2;
        float4 v = *(const float4*)&Z[(size_t)(j0 + jl) * 512 + co0 + c4];
        lds[jl * 65 + c4] = v.x; lds[jl * 65 + c4 + 1] = v.y;
        lds[jl * 65 + c4 + 2] = v.z; lds[jl * 65 + c4 + 3] = v.w;
    }
    __syncthreads();
    #pragma unroll
    for (int it = 0; it < 8; ++it) {
        int idx = tid + (it << 8);
        int col = idx >> 5, j4 = (idx & 31) << 2;
        int j = j0 + j4;
        int n = j / 784;
        int hw = j - n * 784;
        int co = co0 + col;
        float sc = scale[co], sh = shift[co];
        size_t o = (size_t)n * 401408 + (size_t)co * 784 + hw;
        float4 xv = *(const float4*)&x[o];
        float4 r;
        r.x = fmaf(lds[(j4 + 0) * 65 + col], sc, sh) + xv.x;
        r.y = fmaf(lds[(j4 + 1) * 65 + col], sc, sh) + xv.y;
        r.z = fmaf(lds[(j4 + 2) * 65 + col], sc, sh) + xv.z;
        r.w = fmaf(lds[(j4 + 3) * 65 + col], sc, sh) + xv.w;
        *(float4*)&out[o] = r;
    }
}

extern "C" void kernel_launch(void* const* d_in, const int* in_sizes, int n_in,
                              void* d_out, int out_size, void* d_ws, size_t ws_size,
                              hipStream_t stream)
{
    const float* x     = (const float*)d_in[0];
    const float* wg    = (const float*)d_in[1];
    const float* bg    = (const float*)d_in[2];
    const float* wth   = (const float*)d_in[3];
    const float* bth   = (const float*)d_in[4];
    const float* wph   = (const float*)d_in[5];
    const float* bph   = (const float*)d_in[6];
    const float* wW    = (const float*)d_in[7];
    const float* bW    = (const float*)d_in[8];
    const float* gamma = (const float*)d_in[9];
    const float* beta  = (const float*)d_in[10];
    float* out = (float*)d_out;
    float* ws  = (float*)d_ws;

    // workspace layout (f32 units). Aliases: YT2 over dead xT; Z over dead thetaT/G/P/S.
    unsigned short* xTb    = (unsigned short*)ws;                    // 51.4 MB
    unsigned short* YT2    = (unsigned short*)ws;                    // 25.7 MB (alias, xT dead)
    unsigned short* thetaT = (unsigned short*)(ws + 12845056);       // 25.7 MB
    unsigned short* Gv     = (unsigned short*)(ws + 19267584);       // 6.4 MB
    unsigned short* Pv     = (unsigned short*)(ws + 20873216);       // 6.4 MB
    unsigned short* Sb     = (unsigned short*)(ws + 22478848);       // 1.05 MB
    float* Z               = ws + 12845056;                          // 102.8 MB (alias, all dead)
    unsigned short* wthb   = (unsigned short*)(ws + 38535168);
    unsigned short* wgb    = wthb + 131072;
    unsigned short* wphb   = wgb + 131072;
    unsigned short* wW2b   = wphb + 131072;
    float* stats           = ws + 38797312;                          // sum|sq|scale|shift

    zero_kernel<<<2, 1024, 0, stream>>>(stats, 2048);
    castw_kernel<<<2048, 256, 0, stream>>>(wth, wg, wph, wW, wthb, wgb, wphb, wW2b);
    castx_kernel<<<dim3(13, 8, 64), 256, 0, stream>>>(x, xTb);
    proj_theta_kernel<<<dim3(392, 2), 256, 0, stream>>>(xTb, wthb, bth, thetaT);
    proj_gp_kernel<<<dim3(7, 4, 64), 256, 0, stream>>>(xTb, wgb, wphb, bg, bph, Gv, Pv);
    s_kernel<<<dim3(2, 2, 8), 256, 0, stream>>>(Gv, Pv, Sb);
    y_kernel<<<dim3(49, 2, 8), 256, 0, stream>>>(Sb, thetaT, YT2);
    zconv_kernel<<<dim3(392, 4), 256, 0, stream>>>(YT2, wW2b, bW, Z, stats, stats + 512);
    bn_finalize<<<1, 512, 0, stream>>>(stats, stats + 512, gamma, beta,
                                       stats + 1024, stats + 1536);
    bn_apply<<<dim3(392, 8), 256, 0, stream>>>(Z, x, stats + 1024, stats + 1536, out);
}

// Round 3
// 622.011 us; speedup vs baseline: 2.0504x; 1.0068x over previous
//
#include <hip/hip_runtime.h>
#include <stdint.h>

#define BN_EPS 1e-5f

typedef float  f32x4  __attribute__((ext_vector_type(4)));
typedef short  bf16x8 __attribute__((ext_vector_type(8)));

#define MFMA16(a, b, c) __builtin_amdgcn_mfma_f32_16x16x32_bf16((a), (b), (c), 0, 0, 0)

#define GLD16(gsrc, ldst)                                                              \
    __builtin_amdgcn_global_load_lds(                                                  \
        (const __attribute__((address_space(1))) uint32_t*)(gsrc),                     \
        (__attribute__((address_space(3))) uint32_t*)(ldst), 16, 0, 0)

__device__ __forceinline__ unsigned short f2bf(float f) {
    union { float f; uint32_t u; } v; v.f = f;
    uint32_t u = v.u;
    u += 0x7FFF + ((u >> 16) & 1);          // RNE
    return (unsigned short)(u >> 16);
}
__device__ __forceinline__ float bf2f(unsigned short u) {
    union { uint32_t u; float f; } v; v.u = ((uint32_t)u) << 16; return v.f;
}

// ---------------- zero ----------------
__global__ __launch_bounds__(1024) void zero_kernel(float* __restrict__ p, int n) {
    int i = blockIdx.x * blockDim.x + threadIdx.x;
    if (i < n) p[i] = 0.f;
}

// ---------------- cast weights (wth/wg/wph straight, wW permuted) ----------------
__global__ __launch_bounds__(256) void castw_kernel(
    const float* __restrict__ wth, const float* __restrict__ wg,
    const float* __restrict__ wph, const float* __restrict__ wW,
    unsigned short* __restrict__ wthb, unsigned short* __restrict__ wgb,
    unsigned short* __restrict__ wphb, unsigned short* __restrict__ wW2b)
{
    int i = blockIdx.x * 256 + threadIdx.x;
    if (i < 131072) wthb[i] = f2bf(wth[i]);
    else if (i < 262144) wgb[i - 131072] = f2bf(wg[i - 131072]);
    else if (i < 393216) wphb[i - 262144] = f2bf(wph[i - 262144]);
    else {
        int j = i - 393216;                  // [co][k'] with k' = q*32 + a
        int co = j >> 8, k = j & 255;
        int q = k >> 5, a = k & 31;
        wW2b[j] = f2bf(wW[(co << 8) + (a << 3) + q]);
    }
}

// ---------------- cast + transpose x -> xT[(n*784+hw)][512] bf16 ----------------
__global__ __launch_bounds__(256) void castx_kernel(
    const float* __restrict__ x, unsigned short* __restrict__ xT)
{
    __shared__ float lds[64 * 65];
    const int tid = threadIdx.x;
    const int ht = blockIdx.x, ct = blockIdx.y, n = blockIdx.z;
    const int hw0 = ht << 6, ch0 = ct << 6;
    const float* xn = x + (size_t)n * 401408;
    #pragma unroll
    for (int it = 0; it < 16; ++it) {
        int idx = tid + (it << 8);
        int r = idx >> 6, cw = idx & 63;
        int hw = hw0 + cw;
        if (hw < 784) lds[r * 65 + cw] = xn[(size_t)(ch0 + r) * 784 + hw];
    }
    __syncthreads();
    #pragma unroll
    for (int it = 0; it < 8; ++it) {
        int idx = tid + (it << 8);
        int hl = idx >> 5, c2 = (idx & 31) << 1;
        int hw = hw0 + hl;
        if (hw < 784) {
            uint32_t lo = f2bf(lds[c2 * 65 + hl]);
            uint32_t hi = f2bf(lds[(c2 + 1) * 65 + hl]);
            *(uint32_t*)(xT + ((size_t)(n * 784 + hw) << 9) + ch0 + c2) = lo | (hi << 16);
        }
    }
}

// ---------------- proj_theta: theta = wth * x, output thetaT[seg][t][i] ----------------
// grid (392, 2), block 256 (4 waves 2x2), BM=BN=128, BK=32, K=512
__global__ __launch_bounds__(256) void proj_theta_kernel(
    const unsigned short* __restrict__ xT, const unsigned short* __restrict__ wthb,
    const float* __restrict__ bth, unsigned short* __restrict__ thetaT)
{
    __shared__ char smem[32768];             // dbuf 2 x (A 8K | B 8K); epilogue bounce 32K
    const int tid = threadIdx.x, l = tid & 63, w = tid >> 6;
    const int jt = blockIdx.x, mb = blockIdx.y;
    const int m0 = mb << 7, j0 = jt << 7;
    const int wm = w >> 1, wn = w & 1;

    const unsigned short* srcA[2]; const unsigned short* srcB[2];
    #pragma unroll
    for (int i = 0; i < 2; ++i) {
        int c = (w << 7) + (i << 6) + l;     // chunk id 0..511
        int m = c & 127, kc = c >> 7;
        srcA[i] = wthb + (((size_t)(m0 + m)) << 9) + (kc << 3);
        srcB[i] = xT + (((size_t)(j0 + m)) << 9) + (kc << 3);
    }
    // prologue stage step 0 -> buf 0
    #pragma unroll
    for (int i = 0; i < 2; ++i) {
        GLD16(srcA[i], smem + (w << 11) + (i << 10));
        GLD16(srcB[i], smem + 8192 + (w << 11) + (i << 10));
        srcA[i] += 32; srcB[i] += 32;
    }
    f32x4 acc[4][4] = {};
    const int fr = ((l >> 4) << 7) + (l & 15);
    for (int s = 0; s < 16; ++s) {
        __syncthreads();
        char* cur = smem + ((s & 1) << 14);
        if (s + 1 < 16) {
            char* nxt = smem + (((s + 1) & 1) << 14);
            #pragma unroll
            for (int i = 0; i < 2; ++i) {
                GLD16(srcA[i], nxt + (w << 11) + (i << 10));
                GLD16(srcB[i], nxt + 8192 + (w << 11) + (i << 10));
                srcA[i] += 32; srcB[i] += 32;
            }
        }
        bf16x8 a[4], b[4];
        #pragma unroll
        for (int mf = 0; mf < 4; ++mf)
            a[mf] = *(const bf16x8*)(cur + ((fr + (wm << 6) + (mf << 4)) << 4));
        #pragma unroll
        for (int nf = 0; nf < 4; ++nf)
            b[nf] = *(const bf16x8*)(cur + 8192 + ((fr + (wn << 6) + (nf << 4)) << 4));
        #pragma unroll
        for (int mf = 0; mf < 4; ++mf)
            #pragma unroll
            for (int nf = 0; nf < 4; ++nf)
                acc[mf][nf] = MFMA16(a[mf], b[nf], acc[mf][nf]);
    }
    __syncthreads();
    // bounce tile [c_local 128][j_local 128] bf16
    unsigned short* lds16 = (unsigned short*)smem;
    #pragma unroll
    for (int mf = 0; mf < 4; ++mf) {
        int cbase = (wm << 6) + (mf << 4) + ((l >> 4) << 2);
        #pragma unroll
        for (int r = 0; r < 4; ++r) {
            float bv = bth[m0 + cbase + r];
            #pragma unroll
            for (int nf = 0; nf < 4; ++nf) {
                int jl = (wn << 6) + (nf << 4) + (l & 15);
                lds16[(cbase + r) * 128 + jl] = f2bf(acc[mf][nf][r] + bv);
            }
        }
    }
    __syncthreads();
    // scatter to thetaT[seg][t=q*784+hw][i]; i = (n&7)*32 + mb*16 + h*8 + e
    const int jl = tid >> 1, h = tid & 1;
    const int j = j0 + jl;
    const int n = j / 784;
    const int hw = j - n * 784;
    const int seg = n >> 3;
    unsigned short* ob = thetaT + (size_t)seg * 1605632 + ((n & 7) << 5) + (mb << 4) + (h << 3);
    #pragma unroll
    for (int q = 0; q < 8; ++q) {
        uint32_t u[8];
        #pragma unroll
        for (int e = 0; e < 8; ++e)
            u[e] = lds16[(((h << 3) + e) * 8 + q) * 128 + jl];
        uint4 pk;
        pk.x = u[0] | (u[1] << 16); pk.y = u[2] | (u[3] << 16);
        pk.z = u[4] | (u[5] << 16); pk.w = u[6] | (u[7] << 16);
        *(uint4*)(ob + (size_t)(q * 784 + hw) * 256) = pk;
    }
}

// ---------------- proj_gp: g/phi conv + 2x2 maxpool -> Gv/Pv (ref raw layout) ----------------
// grid (7, 4, 64): x = hw-tile(112), y = mb (0-1 g, 2-3 phi), z = image. BM=128, BN=112
__global__ __launch_bounds__(256) void proj_gp_kernel(
    const unsigned short* __restrict__ xT,
    const unsigned short* __restrict__ wgb, const unsigned short* __restrict__ wphb,
    const float* __restrict__ bg, const float* __restrict__ bph,
    unsigned short* __restrict__ Gv, unsigned short* __restrict__ Pv)
{
    __shared__ char smem[30720];             // dbuf 2 x (A 8192 | B 7168)
    const int tid = threadIdx.x, l = tid & 63, w = tid >> 6;
    const int jt = blockIdx.x, mb = blockIdx.y, n = blockIdx.z;
    const int isP = mb >> 1, row0 = (mb & 1) << 7;
    const unsigned short* Wb = isP ? wphb : wgb;
    const int hw0 = jt * 112;

    const unsigned short* srcA[2]; const unsigned short* srcB[2];
    #pragma unroll
    for (int i = 0; i < 2; ++i) {
        int ca = (w << 7) + (i << 6) + l;
        srcA[i] = Wb + (((size_t)(row0 + (ca & 127))) << 9) + ((ca >> 7) << 3);
        int cb = w * 112 + (i << 6) + l;
        int jj = cb % 112, kc = cb / 112;
        srcB[i] = xT + (((size_t)(n * 784 + hw0 + jj)) << 9) + (kc << 3);
    }
    #pragma unroll
    for (int i = 0; i < 2; ++i) {
        GLD16(srcA[i], smem + (w << 11) + (i << 10));
        if (i == 0 || l < 48)
            GLD16(srcB[i], smem + 8192 + w * 1792 + (i << 10));
        srcA[i] += 32; srcB[i] += 32;
    }
    f32x4 acc[2][7] = {};
    for (int s = 0; s < 16; ++s) {
        __syncthreads();
        char* cur = smem + (s & 1) * 15360;
        if (s + 1 < 16) {
            char* nxt = smem + ((s + 1) & 1) * 15360;
            #pragma unroll
            for (int i = 0; i < 2; ++i) {
                GLD16(srcA[i], nxt + (w << 11) + (i << 10));
                if (i == 0 || l < 48)
                    GLD16(srcB[i], nxt + 8192 + w * 1792 + (i << 10));
                srcA[i] += 32; srcB[i] += 32;
            }
        }
        bf16x8 a[2], b[7];
        #pragma unroll
        for (int mf = 0; mf < 2; ++mf)
            a[mf] = *(const bf16x8*)(cur + ((((l >> 4) << 7) + (w << 5) + (mf << 4) + (l & 15)) << 4));
        #pragma unroll
        for (int nf = 0; nf < 7; ++nf)
            b[nf] = *(const bf16x8*)(cur + 8192 + ((((l >> 4) * 112) + (nf << 4) + (l & 15)) << 4));
        #pragma unroll
        for (int mf = 0; mf < 2; ++mf)
            #pragma unroll
            for (int nf = 0; nf < 7; ++nf)
                acc[mf][nf] = MFMA16(a[mf], b[nf], acc[mf][nf]);
    }
    __syncthreads();
    unsigned short* lds16 = (unsigned short*)smem;   // [c 128][hw 112]
    #pragma unroll
    for (int mf = 0; mf < 2; ++mf) {
        int cbase = (w << 5) + (mf << 4) + ((l >> 4) << 2);
        #pragma unroll
        for (int r = 0; r < 4; ++r)
            #pragma unroll
            for (int nf = 0; nf < 7; ++nf) {
                int jl = (nf << 4) + (l & 15);
                lds16[(cbase + r) * 112 + jl] = f2bf(acc[mf][nf][r]);
            }
    }
    __syncthreads();
    // pool 2x2 + bias; write ref-raw layout: seg*401408 + vr*1568 + vp
    const int c_l = tid >> 1, ph_l = tid & 1;
    const int c = row0 + c_l;
    const float bv = (isP ? bph : bg)[c];
    const int seg = n >> 3;
    const int vr = ((n & 7) << 5) + (c >> 3);
    const int vp0 = (c & 7) * 196 + ((jt << 1) + ph_l) * 14;
    unsigned short* outp = (isP ? Pv : Gv) + (size_t)seg * 401408 + (size_t)vr * 1568 + vp0;
    const unsigned short* rowA = lds16 + c_l * 112 + ph_l * 56;
    #pragma unroll
    for (int pw = 0; pw < 14; pw += 2) {
        unsigned short o[2];
        #pragma unroll
        for (int t2 = 0; t2 < 2; ++t2) {
            int wb = (pw + t2) << 1;
            float v0 = bf2f(rowA[wb]),     v1 = bf2f(rowA[wb + 1]);
            float v2 = bf2f(rowA[wb + 28]), v3 = bf2f(rowA[wb + 29]);
            o[t2] = f2bf(fmaxf(fmaxf(v0, v1), fmaxf(v2, v3)) + bv);
        }
        *(ushort2*)(outp + pw) = make_ushort2(o[0], o[1]);
    }
}

// ---------------- s_kernel: S = G * P^T / 1568, bf16 out ----------------
// grid (2, 2, 8), BM=BN=128, K=1568 (49 steps)
__global__ __launch_bounds__(256) void s_kernel(
    const unsigned short* __restrict__ Gv, const unsigned short* __restrict__ Pv,
    unsigned short* __restrict__ Sb)
{
    __shared__ char smem[32768];
    const int tid = threadIdx.x, l = tid & 63, w = tid >> 6;
    const int m0 = blockIdx.x << 7, n0 = blockIdx.y << 7, seg = blockIdx.z;
    const int wm = w >> 1, wn = w & 1;
    const unsigned short* srcA[2]; const unsigned short* srcB[2];
    #pragma unroll
    for (int i = 0; i < 2; ++i) {
        int c = (w << 7) + (i << 6) + l;
        srcA[i] = Gv + (size_t)seg * 401408 + (size_t)(m0 + (c & 127)) * 1568 + ((c >> 7) << 3);
        srcB[i] = Pv + (size_t)seg * 401408 + (size_t)(n0 + (c & 127)) * 1568 + ((c >> 7) << 3);
    }
    #pragma unroll
    for (int i = 0; i < 2; ++i) {
        GLD16(srcA[i], smem + (w << 11) + (i << 10));
        GLD16(srcB[i], smem + 8192 + (w << 11) + (i << 10));
        srcA[i] += 32; srcB[i] += 32;
    }
    f32x4 acc[4][4] = {};
    const int fr = ((l >> 4) << 7) + (l & 15);
    for (int s = 0; s < 49; ++s) {
        __syncthreads();
        char* cur = smem + ((s & 1) << 14);
        if (s + 1 < 49) {
            char* nxt = smem + (((s + 1) & 1) << 14);
            #pragma unroll
            for (int i = 0; i < 2; ++i) {
                GLD16(srcA[i], nxt + (w << 11) + (i << 10));
                GLD16(srcB[i], nxt + 8192 + (w << 11) + (i << 10));
                srcA[i] += 32; srcB[i] += 32;
            }
        }
        bf16x8 a[4], b[4];
        #pragma unroll
        for (int mf = 0; mf < 4; ++mf)
            a[mf] = *(const bf16x8*)(cur + ((fr + (wm << 6) + (mf << 4)) << 4));
        #pragma unroll
        for (int nf = 0; nf < 4; ++nf)
            b[nf] = *(const bf16x8*)(cur + 8192 + ((fr + (wn << 6) + (nf << 4)) << 4));
        #pragma unroll
        for (int mf = 0; mf < 4; ++mf)
            #pragma unroll
            for (int nf = 0; nf < 4; ++nf)
                acc[mf][nf] = MFMA16(a[mf], b[nf], acc[mf][nf]);
    }
    __syncthreads();
    unsigned short* lds16 = (unsigned short*)smem;   // [c 128][i 128]
    const float sc = 1.f / 1568.f;
    #pragma unroll
    for (int mf = 0; mf < 4; ++mf) {
        int cbase = (wm << 6) + (mf << 4) + ((l >> 4) << 2);
        #pragma unroll
        for (int r = 0; r < 4; ++r)
            #pragma unroll
            for (int nf = 0; nf < 4; ++nf) {
                int il = (wn << 6) + (nf << 4) + (l & 15);
                lds16[(cbase + r) * 128 + il] = f2bf(acc[mf][nf][r] * sc);
            }
    }
    __syncthreads();
    #pragma unroll
    for (int it = 0; it < 8; ++it) {
        int idx = tid + (it << 8);
        int crow = idx >> 4, ic = idx & 15;
        uint4 pk = *(const uint4*)(lds16 + crow * 128 + (ic << 3));
        *(uint4*)(Sb + (size_t)seg * 65536 + (size_t)(m0 + crow) * 256 + n0 + (ic << 3)) = pk;
    }
}

// ---------------- y_kernel: Y = S * Tv -> YT2[seg][t][c] bf16 ----------------
// grid (49, 2, 8), BM=BN=128, K=256 (8 steps)
__global__ __launch_bounds__(256) void y_kernel(
    const unsigned short* __restrict__ Sb, const unsigned short* __restrict__ thetaT,
    unsigned short* __restrict__ YT2)
{
    __shared__ char smem[32768];
    const int tid = threadIdx.x, l = tid & 63, w = tid >> 6;
    const int jt = blockIdx.x, mt = blockIdx.y, seg = blockIdx.z;
    const int m0 = mt << 7, t0 = jt << 7;
    const int wm = w >> 1, wn = w & 1;
    const unsigned short* srcA[2]; const unsigned short* srcB[2];
    #pragma unroll
    for (int i = 0; i < 2; ++i) {
        int c = (w << 7) + (i << 6) + l;
        srcA[i] = Sb + (size_t)seg * 65536 + (size_t)(m0 + (c & 127)) * 256 + ((c >> 7) << 3);
        srcB[i] = thetaT + (size_t)seg * 1605632 + (size_t)(t0 + (c & 127)) * 256 + ((c >> 7) << 3);
    }
    #pragma unroll
    for (int i = 0; i < 2; ++i) {
        GLD16(srcA[i], smem + (w << 11) + (i << 10));
        GLD16(srcB[i], smem + 8192 + (w << 11) + (i << 10));
        srcA[i] += 32; srcB[i] += 32;
    }
    f32x4 acc[4][4] = {};
    const int fr = ((l >> 4) << 7) + (l & 15);
    for (int s = 0; s < 8; ++s) {
        __syncthreads();
        char* cur = smem + ((s & 1) << 14);
        if (s + 1 < 8) {
            char* nxt = smem + (((s + 1) & 1) << 14);
            #pragma unroll
            for (int i = 0; i < 2; ++i) {
                GLD16(srcA[i], nxt + (w << 11) + (i << 10));
                GLD16(srcB[i], nxt + 8192 + (w << 11) + (i << 10));
                srcA[i] += 32; srcB[i] += 32;
            }
        }
        bf16x8 a[4], b[4];
        #pragma unroll
        for (int mf = 0; mf < 4; ++mf)
            a[mf] = *(const bf16x8*)(cur + ((fr + (wm << 6) + (mf << 4)) << 4));
        #pragma unroll
        for (int nf = 0; nf < 4; ++nf)
            b[nf] = *(const bf16x8*)(cur + 8192 + ((fr + (wn << 6) + (nf << 4)) << 4));
        #pragma unroll
        for (int mf = 0; mf < 4; ++mf)
            #pragma unroll
            for (int nf = 0; nf < 4; ++nf)
                acc[mf][nf] = MFMA16(a[mf], b[nf], acc[mf][nf]);
    }
    __syncthreads();
    unsigned short* lds16 = (unsigned short*)smem;   // [c 128][t 128]
    #pragma unroll
    for (int mf = 0; mf < 4; ++mf) {
        int cbase = (wm << 6) + (mf << 4) + ((l >> 4) << 2);
        #pragma unroll
        for (int r = 0; r < 4; ++r)
            #pragma unroll
            for (int nf = 0; nf < 4; ++nf) {
                int jl = (wn << 6) + (nf << 4) + (l & 15);
                lds16[(cbase + r) * 128 + jl] = f2bf(acc[mf][nf][r]);
            }
    }
    __syncthreads();
    #pragma unroll
    for (int it = 0; it < 8; ++it) {
        int idx = tid + (it << 8);
        int jl = idx >> 4, cc = idx & 15;
        uint32_t u[8];
        #pragma unroll
        for (int e = 0; e < 8; ++e)
            u[e] = lds16[((cc << 3) + e) * 128 + jl];
        uint4 pk;
        pk.x = u[0] | (u[1] << 16); pk.y = u[2] | (u[3] << 16);
        pk.z = u[4] | (u[5] << 16); pk.w = u[6] | (u[7] << 16);
        *(uint4*)(YT2 + (size_t)seg * 1605632 + (size_t)(t0 + jl) * 256 + m0 + (cc << 3)) = pk;
    }
}

// ---------------- zconv_stats: Z = wW2*YT2 + bW in-register, only BN sums out ----------------
// grid (392, 4), BM=128 co, BN=128 j, K=256 (8 steps over q)
__global__ __launch_bounds__(256) void zconv_stats_kernel(
    const unsigned short* __restrict__ YT2, const unsigned short* __restrict__ wW2b,
    const float* __restrict__ bW,
    float* __restrict__ sumB, float* __restrict__ sqB)
{
    __shared__ char smem[32768];
    const int tid = threadIdx.x, l = tid & 63, w = tid >> 6;
    const int jt = blockIdx.x, mt = blockIdx.y;
    const int m0 = mt << 7, j0 = jt << 7;
    const int wm = w >> 1, wn = w & 1;
    const unsigned short* srcA[2]; const unsigned short* srcB[2];
    #pragma unroll
    for (int i = 0; i < 2; ++i) {
        int c = (w << 7) + (i << 6) + l;
        int jj = c & 127, kc = c >> 7;
        srcA[i] = wW2b + (size_t)(m0 + jj) * 256 + (kc << 3);
        int j = j0 + jj;
        int nimg = j / 784;
        int hw = j - nimg * 784;
        srcB[i] = YT2 + (size_t)(nimg >> 3) * 1605632 + (size_t)hw * 256 + ((nimg & 7) << 5) + (kc << 3);
    }
    #pragma unroll
    for (int i = 0; i < 2; ++i) {
        GLD16(srcA[i], smem + (w << 11) + (i << 10));
        GLD16(srcB[i], smem + 8192 + (w << 11) + (i << 10));
        srcA[i] += 32; srcB[i] += 200704;       // next q: +784*256 elements
    }
    f32x4 acc[4][4] = {};
    const int fr = ((l >> 4) << 7) + (l & 15);
    for (int s = 0; s < 8; ++s) {
        __syncthreads();
        char* cur = smem + ((s & 1) << 14);
        if (s + 1 < 8) {
            char* nxt = smem + (((s + 1) & 1) << 14);
            #pragma unroll
            for (int i = 0; i < 2; ++i) {
                GLD16(srcA[i], nxt + (w << 11) + (i << 10));
                GLD16(srcB[i], nxt + 8192 + (w << 11) + (i << 10));
                srcA[i] += 32; srcB[i] += 200704;
            }
        }
        bf16x8 a[4], b[4];
        #pragma unroll
        for (int mf = 0; mf < 4; ++mf)
            a[mf] = *(const bf16x8*)(cur + ((fr + (wm << 6) + (mf << 4)) << 4));
        #pragma unroll
        for (int nf = 0; nf < 4; ++nf)
            b[nf] = *(const bf16x8*)(cur + 8192 + ((fr + (wn << 6) + (nf << 4)) << 4));
        #pragma unroll
        for (int mf = 0; mf < 4; ++mf)
            #pragma unroll
            for (int nf = 0; nf < 4; ++nf)
                acc[mf][nf] = MFMA16(a[mf], b[nf], acc[mf][nf]);
    }
    // epilogue: per-channel sums only (no Z store)
    #pragma unroll
    for (int mf = 0; mf < 4; ++mf) {
        int co = m0 + (wm << 6) + (mf << 4) + ((l >> 4) << 2);
        float4 bv = *(const float4*)&bW[co];
        float s1[4] = {0, 0, 0, 0}, s2[4] = {0, 0, 0, 0};
        #pragma unroll
        for (int nf = 0; nf < 4; ++nf) {
            float4 o;
            o.x = acc[mf][nf][0] + bv.x; o.y = acc[mf][nf][1] + bv.y;
            o.z = acc[mf][nf][2] + bv.z; o.w = acc[mf][nf][3] + bv.w;
            s1[0] += o.x; s2[0] += o.x * o.x;
            s1[1] += o.y; s2[1] += o.y * o.y;
            s1[2] += o.z; s2[2] += o.z * o.z;
            s1[3] += o.w; s2[3] += o.w * o.w;
        }
        #pragma unroll
        for (int off = 1; off < 16; off <<= 1)
            #pragma unroll
            for (int r = 0; r < 4; ++r) {
                s1[r] += __shfl_xor(s1[r], off);
                s2[r] += __shfl_xor(s2[r], off);
            }
        if ((l & 15) == 0)
            #pragma unroll
            for (int r = 0; r < 4; ++r) {
                atomicAdd(&sumB[co + r], s1[r]);
                atomicAdd(&sqB[co + r], s2[r]);
            }
    }
}

// ---------------- BN finalize (folds bW into shift) ----------------
__global__ __launch_bounds__(512) void bn_finalize(
    const float* __restrict__ sumB, const float* __restrict__ sqB,
    const float* __restrict__ gamma, const float* __restrict__ beta,
    const float* __restrict__ bW,
    float* __restrict__ scale, float* __restrict__ shift2)
{
    int c = threadIdx.x;
    if (c < 512) {
        const float invN = 1.f / 50176.f;
        float mean = sumB[c] * invN;
        float var = sqB[c] * invN - mean * mean;
        float inv = rsqrtf(var + BN_EPS);
        float sc = gamma[c] * inv;
        scale[c] = sc;
        shift2[c] = bW[c] * sc + beta[c] - mean * sc;   // out = acc*sc + shift2 + x
    }
}

// ---------------- bn_apply: recompute Z tile, apply BN + residual, coalesced out ----------------
// grid (7, 4, 64): jt (112 hw), mt (128 co), n. BM=128 co, BN=112 j, K=256 (8 steps)
__global__ __launch_bounds__(256) void bn_apply_kernel(
    const unsigned short* __restrict__ YT2, const unsigned short* __restrict__ wW2b,
    const float* __restrict__ scale, const float* __restrict__ shift2,
    const float* __restrict__ x, float* __restrict__ out)
{
    __shared__ char smem[30720];             // dbuf 2 x (A 8192 | B 7168); epilogue 29696
    const int tid = threadIdx.x, l = tid & 63, w = tid >> 6;
    const int jt = blockIdx.x, mt = blockIdx.y, n = blockIdx.z;
    const int co0 = mt << 7;
    const int hwb = jt * 112;
    const size_t ybase = (size_t)(n >> 3) * 1605632 + ((n & 7) << 5);

    const unsigned short* srcA[2]; const unsigned short* srcB[2];
    #pragma unroll
    for (int i = 0; i < 2; ++i) {
        int ca = (w << 7) + (i << 6) + l;
        srcA[i] = wW2b + (size_t)(co0 + (ca & 127)) * 256 + ((ca >> 7) << 3);
        int cb = w * 112 + (i << 6) + l;
        int jj = cb % 112, kc = cb / 112;
        srcB[i] = YT2 + ybase + (size_t)(hwb + jj) * 256 + (kc << 3);
    }
    #pragma unroll
    for (int i = 0; i < 2; ++i) {
        GLD16(srcA[i], smem + (w << 11) + (i << 10));
        if (i == 0 || l < 48)
            GLD16(srcB[i], smem + 8192 + w * 1792 + (i << 10));
        srcA[i] += 32; srcB[i] += 200704;       // next q
    }
    f32x4 acc[2][7] = {};
    for (int s = 0; s < 8; ++s) {
        __syncthreads();
        char* cur = smem + (s & 1) * 15360;
        if (s + 1 < 8) {
            char* nxt = smem + ((s + 1) & 1) * 15360;
            #pragma unroll
            for (int i = 0; i < 2; ++i) {
                GLD16(srcA[i], nxt + (w << 11) + (i << 10));
                if (i == 0 || l < 48)
                    GLD16(srcB[i], nxt + 8192 + w * 1792 + (i << 10));
                srcA[i] += 32; srcB[i] += 200704;
            }
        }
        bf16x8 a[2], b[7];
        #pragma unroll
        for (int mf = 0; mf < 2; ++mf)
            a[mf] = *(const bf16x8*)(cur + ((((l >> 4) << 7) + (w << 5) + (mf << 4) + (l & 15)) << 4));
        #pragma unroll
        for (int nf = 0; nf < 7; ++nf)
            b[nf] = *(const bf16x8*)(cur + 8192 + ((((l >> 4) * 112) + (nf << 4) + (l & 15)) << 4));
        #pragma unroll
        for (int mf = 0; mf < 2; ++mf)
            #pragma unroll
            for (int nf = 0; nf < 7; ++nf)
                acc[mf][nf] = MFMA16(a[mf], b[nf], acc[mf][nf]);
    }
    // epilogue: two co-halves of 64 x 112 f32 through LDS, coalesced float4 out
    float* ldsf = (float*)smem;              // stride 116 floats (29 float4, 16B aligned)
    #pragma unroll
    for (int h2 = 0; h2 < 2; ++h2) {
        __syncthreads();
        if ((w >> 1) == h2) {
            #pragma unroll
            for (int mf = 0; mf < 2; ++mf) {
                int rbase = ((w & 1) << 5) + (mf << 4) + ((l >> 4) << 2);
                #pragma unroll
                for (int r = 0; r < 4; ++r)
                    #pragma unroll
                    for (int nf = 0; nf < 7; ++nf)
                        ldsf[(rbase + r) * 116 + (nf << 4) + (l & 15)] = acc[mf][nf][r];
            }
        }
        __syncthreads();
        #pragma unroll
        for (int it = 0; it < 7; ++it) {     // 64 rows x 28 quads = 1792 = 7*256
            int idx = tid + (it << 8);
            int rl = idx / 28, jq = idx - rl * 28;
            int co = co0 + (h2 << 6) + rl;
            float sc = scale[co], sh = shift2[co];
            size_t o = (size_t)n * 401408 + (size_t)co * 784 + hwb + (jq << 2);
            float4 z = *(const float4*)&ldsf[rl * 116 + (jq << 2)];
            float4 xv = *(const float4*)&x[o];
            float4 rv;
            rv.x = fmaf(z.x, sc, sh) + xv.x;
            rv.y = fmaf(z.y, sc, sh) + xv.y;
            rv.z = fmaf(z.z, sc, sh) + xv.z;
            rv.w = fmaf(z.w, sc, sh) + xv.w;
            *(float4*)&out[o] = rv;
        }
    }
}

extern "C" void kernel_launch(void* const* d_in, const int* in_sizes, int n_in,
                              void* d_out, int out_size, void* d_ws, size_t ws_size,
                              hipStream_t stream)
{
    const float* x     = (const float*)d_in[0];
    const float* wg    = (const float*)d_in[1];
    const float* bg    = (const float*)d_in[2];
    const float* wth   = (const float*)d_in[3];
    const float* bth   = (const float*)d_in[4];
    const float* wph   = (const float*)d_in[5];
    const float* bph   = (const float*)d_in[6];
    const float* wW    = (const float*)d_in[7];
    const float* bW    = (const float*)d_in[8];
    const float* gamma = (const float*)d_in[9];
    const float* beta  = (const float*)d_in[10];
    float* out = (float*)d_out;
    float* ws  = (float*)d_ws;

    // workspace layout (f32 units). Alias: YT2 over dead xT region.
    unsigned short* xTb    = (unsigned short*)ws;                    // 51.4 MB
    unsigned short* YT2    = (unsigned short*)ws;                    // 25.7 MB (alias, xT dead)
    unsigned short* thetaT = (unsigned short*)(ws + 12845056);       // 25.7 MB
    unsigned short* Gv     = (unsigned short*)(ws + 19267584);       // 6.4 MB
    unsigned short* Pv     = (unsigned short*)(ws + 20873216);       // 6.4 MB
    unsigned short* Sb     = (unsigned short*)(ws + 22478848);       // 1.05 MB
    unsigned short* wthb   = (unsigned short*)(ws + 38535168);
    unsigned short* wgb    = wthb + 131072;
    unsigned short* wphb   = wgb + 131072;
    unsigned short* wW2b   = wphb + 131072;
    float* stats           = ws + 38797312;                          // sum|sq|scale|shift2

    zero_kernel<<<2, 1024, 0, stream>>>(stats, 2048);
    castw_kernel<<<2048, 256, 0, stream>>>(wth, wg, wph, wW, wthb, wgb, wphb, wW2b);
    castx_kernel<<<dim3(13, 8, 64), 256, 0, stream>>>(x, xTb);
    proj_theta_kernel<<<dim3(392, 2), 256, 0, stream>>>(xTb, wthb, bth, thetaT);
    proj_gp_kernel<<<dim3(7, 4, 64), 256, 0, stream>>>(xTb, wgb, wphb, bg, bph, Gv, Pv);
    s_kernel<<<dim3(2, 2, 8), 256, 0, stream>>>(Gv, Pv, Sb);
    y_kernel<<<dim3(49, 2, 8), 256, 0, stream>>>(Sb, thetaT, YT2);
    zconv_stats_kernel<<<dim3(392, 4), 256, 0, stream>>>(YT2, wW2b, bW, stats, stats + 512);
    bn_finalize<<<1, 512, 0, stream>>>(stats, stats + 512, gamma, beta, bW,
                                       stats + 1024, stats + 1536);
    bn_apply_kernel<<<dim3(7, 4, 64), 256, 0, stream>>>(YT2, wW2b, stats + 1024,
                                                        stats + 1536, x, out);
}